// Round 1
// baseline (10473.207 us; speedup 1.0000x reference)
//
#include <hip/hip_runtime.h>

#define T_LEN 16384

__device__ __forceinline__ float fast_exp2(float x) { return __builtin_amdgcn_exp2f(x); }
__device__ __forceinline__ float fast_rcp(float x)  { return __builtin_amdgcn_rcpf(x); }
__device__ __forceinline__ float fast_tanh(float x) {
  return 1.f - 2.f * fast_rcp(1.f + fast_exp2(x * 2.885390081777927f));
}
__device__ __forceinline__ float fast_sig(float x) {
  return fast_rcp(1.f + fast_exp2(-x * 1.4426950408889634f));
}

// h/skip global layout: float4 index ((b*8 + j) * T_LEN + t), j = channel quad.
//
// layer_k v2: lane-pair output split. idx = 2*tt + half; each thread computes
// 16 of the 32 output channels for its t. Live accumulator set drops from
// 128 floats (spill-bound at 2 waves/SIMD) to ~96, and the grid doubles to
// 1024 blocks -> 4 blocks/CU, 4 waves/SIMD (50% occupancy). The a[] exchange
// between the two halves of a pair is 16 __shfl_xor — no barrier.
// All register arrays are indexed with compile-time constants; runtime `half`
// only selects values via ?: (v_cndmask), never indexes a register array.

// ---------------- input projection 256->32 ----------------
__global__ __launch_bounds__(256, 2) void in_k(
    const float* __restrict__ x, const float* __restrict__ w,
    const float* __restrict__ bias, float4* __restrict__ h, float4* __restrict__ skip)
{
  __shared__ float4 W[256][8];   // [c][o4] = w[(o4*4+j)*256 + c]
  __shared__ float B[32];
  const int tid = threadIdx.x;
  for (int i = tid; i < 2048; i += 256) {
    int c = i >> 3, o4 = i & 7;
    W[c][o4] = make_float4(w[(o4*4+0)*256 + c], w[(o4*4+1)*256 + c],
                           w[(o4*4+2)*256 + c], w[(o4*4+3)*256 + c]);
  }
  if (tid < 32) B[tid] = bias[tid];
  __syncthreads();

  const int idx = blockIdx.x * 256 + tid;       // 0 .. 131071
  const int b = idx >> 14;
  const int t = idx & (T_LEN - 1);
  const float* xb = x + (size_t)b * 256 * T_LEN + t;

  float acc[32];
  #pragma unroll
  for (int o = 0; o < 32; o++) acc[o] = B[o];
  #pragma unroll 4
  for (int c = 0; c < 256; c++) {
    float v = xb[(size_t)c * T_LEN];
    #pragma unroll
    for (int o4 = 0; o4 < 8; o4++) {
      float4 ww = W[c][o4];
      acc[o4*4+0] += ww.x * v; acc[o4*4+1] += ww.y * v;
      acc[o4*4+2] += ww.z * v; acc[o4*4+3] += ww.w * v;
    }
  }
  #pragma unroll
  for (int j = 0; j < 8; j++) {
    size_t p = ((size_t)(b * 8 + j) << 14) + t;
    h[p]    = make_float4(acc[j*4+0], acc[j*4+1], acc[j*4+2], acc[j*4+3]);
    skip[p] = make_float4(0.f, 0.f, 0.f, 0.f);
  }
}

// ---------------- one residual layer (lane-pair split) ----------------
__global__ __launch_bounds__(256, 4) void layer_k(
    const float4* __restrict__ hin, float4* __restrict__ hout, float4* __restrict__ skip,
    const float* __restrict__ cw, const float* __restrict__ cb,
    const float* __restrict__ gw, const float* __restrict__ gb,
    const float* __restrict__ rw, const float* __restrict__ rb,
    const float* __restrict__ sw, const float* __restrict__ sb, int d)
{
  __shared__ float4 WCG[32][32];  // [ic][o] = (wc0, wc1, wg0, wg1)
  __shared__ float2 WRS[32][32];  // [ic][o] = (wr, ws)
  __shared__ float BC[32], BG[32], BR[32], BS[32];
  const int tid = threadIdx.x;
  // staging: lane-consecutive o -> contiguous LDS writes (conflict-free)
  for (int i = tid; i < 1024; i += 256) {
    int o = i & 31, ic = i >> 5;
    int q = (o * 32 + ic) * 2;
    WCG[ic][o] = make_float4(cw[q], cw[q+1], gw[q], gw[q+1]);
    WRS[ic][o] = make_float2(rw[o*32+ic], sw[o*32+ic]);
  }
  if (tid < 32) { BC[tid]=cb[tid]; BG[tid]=gb[tid]; BR[tid]=rb[tid]; BS[tid]=sb[tid]; }
  __syncthreads();

  const int idx  = blockIdx.x * 256 + tid;   // 0 .. 262143
  const int half = idx & 1;                  // which 16 output channels
  const int tt   = idx >> 1;                 // 0 .. 131071
  const int b = tt >> 14;
  const int t = tt & (T_LEN - 1);
  const int ob = half << 4;                  // output channel base (0 or 16)
  const size_t base = ((size_t)b * 8 << 14) + t;   // + j*T_LEN

  float ht[32], htd[32];
  #pragma unroll
  for (int j = 0; j < 8; j++) {
    float4 v = hin[base + ((size_t)j << 14)];
    ht[j*4+0]=v.x; ht[j*4+1]=v.y; ht[j*4+2]=v.z; ht[j*4+3]=v.w;
  }
  if (t >= d) {
    #pragma unroll
    for (int j = 0; j < 8; j++) {
      float4 v = hin[base + ((size_t)j << 14) - (size_t)d];
      htd[j*4+0]=v.x; htd[j*4+1]=v.y; htd[j*4+2]=v.z; htd[j*4+3]=v.w;
    }
  } else {
    #pragma unroll
    for (int j = 0; j < 32; j++) htd[j] = 0.f;
  }

  // conv + gate: 16 outputs per thread
  float p[16], g[16];
  #pragma unroll
  for (int o = 0; o < 16; o++) { p[o] = BC[ob+o]; g[o] = BG[ob+o]; }
  #pragma unroll
  for (int ic = 0; ic < 32; ic++) {
    float a0 = htd[ic], a1 = ht[ic];
    #pragma unroll
    for (int o = 0; o < 16; o++) {
      float4 w = WCG[ic][ob+o];
      p[o] += w.x * a0 + w.y * a1;
      g[o] += w.z * a0 + w.w * a1;
    }
  }

  float av[16];
  #pragma unroll
  for (int o = 0; o < 16; o++) av[o] = fast_tanh(p[o]) * fast_sig(g[o]);

  // exchange: partner lane (same t, other half) is lane^1
  float ao[16];
  #pragma unroll
  for (int o = 0; o < 16; o++) ao[o] = __shfl_xor(av[o], 1, 64);

  float aa[32];
  #pragma unroll
  for (int k = 0; k < 16; k++) {
    aa[k]      = half ? ao[k] : av[k];
    aa[16 + k] = half ? av[k] : ao[k];
  }

  // prefetch skip (consumed at the very end; latency hidden under res/skip matmul)
  float4 sv[4];
  #pragma unroll
  for (int j = 0; j < 4; j++) sv[j] = skip[base + ((size_t)(half*4 + j) << 14)];

  float hn[16], sk[16];
  #pragma unroll
  for (int o = 0; o < 16; o++) {
    hn[o] = (half ? ht[16 + o] : ht[o]) + BR[ob+o];
    sk[o] = BS[ob+o];
  }
  #pragma unroll
  for (int ic = 0; ic < 32; ic++) {
    float v = aa[ic];
    #pragma unroll
    for (int o = 0; o < 16; o++) {
      float2 w = WRS[ic][ob+o];
      hn[o] += w.x * v;
      sk[o] += w.y * v;
    }
  }

  #pragma unroll
  for (int j = 0; j < 4; j++) {
    size_t p4 = base + ((size_t)(half*4 + j) << 14);
    hout[p4] = make_float4(hn[j*4+0], hn[j*4+1], hn[j*4+2], hn[j*4+3]);
    float4 s = sv[j];
    s.x += sk[j*4+0]; s.y += sk[j*4+1]; s.z += sk[j*4+2]; s.w += sk[j*4+3];
    skip[p4] = s;
  }
}

// ---------------- out: relu(W1 @ skip + b1) -> W2 @ . + b2 ----------------
__global__ __launch_bounds__(256, 2) void out_k(
    const float4* __restrict__ skip,
    const float* __restrict__ w1, const float* __restrict__ b1,
    const float* __restrict__ w2, const float* __restrict__ b2,
    float* __restrict__ out)
{
  __shared__ float4 W1[32][8];    // [ic][o4]
  __shared__ float4 W2[32][64];   // [ic][o4]
  __shared__ float B1[32];
  __shared__ float B2[256];
  const int tid = threadIdx.x;
  {
    int ic = tid >> 3, o4 = tid & 7;
    W1[ic][o4] = make_float4(w1[(o4*4+0)*32+ic], w1[(o4*4+1)*32+ic],
                             w1[(o4*4+2)*32+ic], w1[(o4*4+3)*32+ic]);
  }
  for (int e = tid; e < 2048; e += 256) {
    int ic = e >> 6, o4 = e & 63;
    W2[ic][o4] = make_float4(w2[(o4*4+0)*32+ic], w2[(o4*4+1)*32+ic],
                             w2[(o4*4+2)*32+ic], w2[(o4*4+3)*32+ic]);
  }
  B2[tid & 255] = b2[tid & 255];
  if (tid < 32) B1[tid] = b1[tid];
  __syncthreads();

  const int idx = blockIdx.x * 256 + tid;
  const int b = idx >> 14;
  const int t = idx & (T_LEN - 1);
  const size_t base = ((size_t)b * 8 << 14) + t;

  float sk[32];
  #pragma unroll
  for (int j = 0; j < 8; j++) {
    float4 v = skip[base + ((size_t)j << 14)];
    sk[j*4+0]=v.x; sk[j*4+1]=v.y; sk[j*4+2]=v.z; sk[j*4+3]=v.w;
  }

  float r[32];
  #pragma unroll
  for (int o = 0; o < 32; o++) r[o] = B1[o];
  #pragma unroll
  for (int ic = 0; ic < 32; ic++) {
    float v = sk[ic];
    #pragma unroll
    for (int o4 = 0; o4 < 8; o4++) {
      float4 w = W1[ic][o4];
      r[o4*4+0] += w.x * v; r[o4*4+1] += w.y * v;
      r[o4*4+2] += w.z * v; r[o4*4+3] += w.w * v;
    }
  }
  #pragma unroll
  for (int o = 0; o < 32; o++) r[o] = fmaxf(r[o], 0.f);

  float* ob = out + (size_t)b * 256 * T_LEN + t;
  #pragma unroll 2
  for (int o4 = 0; o4 < 64; o4++) {
    float a0 = B2[o4*4+0], a1 = B2[o4*4+1], a2 = B2[o4*4+2], a3 = B2[o4*4+3];
    #pragma unroll
    for (int ic = 0; ic < 32; ic++) {
      float4 w = W2[ic][o4];
      float v = r[ic];
      a0 += w.x * v; a1 += w.y * v; a2 += w.z * v; a3 += w.w * v;
    }
    ob[(size_t)(o4*4+0)*T_LEN] = a0;
    ob[(size_t)(o4*4+1)*T_LEN] = a1;
    ob[(size_t)(o4*4+2)*T_LEN] = a2;
    ob[(size_t)(o4*4+3)*T_LEN] = a3;
  }
}

extern "C" void kernel_launch(void* const* d_in, const int* in_sizes, int n_in,
                              void* d_out, int out_size, void* d_ws, size_t ws_size,
                              hipStream_t stream)
{
  const float* x    = (const float*)d_in[0];
  const float* in_w = (const float*)d_in[1];
  const float* in_b = (const float*)d_in[2];
  const float* cw   = (const float*)d_in[3];
  const float* cb   = (const float*)d_in[4];
  const float* gw   = (const float*)d_in[5];
  const float* gb   = (const float*)d_in[6];
  const float* rw   = (const float*)d_in[7];
  const float* rb   = (const float*)d_in[8];
  const float* sw   = (const float*)d_in[9];
  const float* sb   = (const float*)d_in[10];
  const float* w1   = (const float*)d_in[11];
  const float* b1   = (const float*)d_in[12];
  const float* w2   = (const float*)d_in[13];
  const float* b2   = (const float*)d_in[14];
  float* out = (float*)d_out;

  // h ping-pong (2 x 16 MB) in d_out scratch (overwritten by out_k); skip in d_ws.
  float4* h0   = (float4*)out;               // 1,048,576 float4s each
  float4* h1   = (float4*)(out + 4194304);
  float4* skip = (float4*)d_ws;

  dim3 blk(256);
  in_k<<<dim3(512), blk, 0, stream>>>(x, in_w, in_b, h0, skip);

  float4* ha = h0;
  float4* hb = h1;
  for (int l = 0; l < 40; l++) {
    int d = 1 << (l % 10);
    layer_k<<<dim3(1024), blk, 0, stream>>>(ha, hb, skip,
        cw + (size_t)l * 2048, cb + l * 32,
        gw + (size_t)l * 2048, gb + l * 32,
        rw + (size_t)l * 1024, rb + l * 32,
        sw + (size_t)l * 1024, sb + l * 32, d);
    float4* tmp = ha; ha = hb; hb = tmp;
  }

  out_k<<<dim3(512), blk, 0, stream>>>(skip, w1, b1, w2, b2, out);
}

// Round 2
// 2646.176 us; speedup vs baseline: 3.9579x; 3.9579x over previous
//
#include <hip/hip_runtime.h>

#define T_LEN 16384

__device__ __forceinline__ float fast_exp2(float x) { return __builtin_amdgcn_exp2f(x); }
__device__ __forceinline__ float fast_rcp(float x)  { return __builtin_amdgcn_rcpf(x); }
__device__ __forceinline__ float fast_tanh(float x) {
  return 1.f - 2.f * fast_rcp(1.f + fast_exp2(x * 2.885390081777927f));
}
__device__ __forceinline__ float fast_sig(float x) {
  return fast_rcp(1.f + fast_exp2(-x * 1.4426950408889634f));
}

// h/skip global layout: float4 index ((b*8 + j) * T_LEN + t), j = channel quad.
//
// layer_k v3: lane-pair output split, 1024 blocks (4 blocks/CU).
// LAUNCH BOUNDS: empirically on this toolchain the VGPR cap is 256/min_waves:
// (256,2) -> 128 VGPRs (spill-free, round 0), (256,4) -> 64 VGPRs (catastrophic
// spill, round 1: 860 MB HBM/layer, 17x ideal). So (256,2) everywhere; the
// reduced live set (~96 floats) lands <=128 and 4 blocks/CU fit naturally.
//
// LDS interleave: lane pair halves read output channels o and o+16. With
// natural layout those are 256 B apart -> same bank (2-way conflict, 8.4M/layer
// in round 1). Interleaved position ((o&15)<<1)|(o>>4) puts them on adjacent
// banks -> conflict-free.

// ---------------- input projection 256->32 ----------------
__global__ __launch_bounds__(256, 2) void in_k(
    const float* __restrict__ x, const float* __restrict__ w,
    const float* __restrict__ bias, float4* __restrict__ h, float4* __restrict__ skip)
{
  __shared__ float4 W[256][8];   // [c][o4] = w[(o4*4+j)*256 + c]
  __shared__ float B[32];
  const int tid = threadIdx.x;
  for (int i = tid; i < 2048; i += 256) {
    int c = i >> 3, o4 = i & 7;
    W[c][o4] = make_float4(w[(o4*4+0)*256 + c], w[(o4*4+1)*256 + c],
                           w[(o4*4+2)*256 + c], w[(o4*4+3)*256 + c]);
  }
  if (tid < 32) B[tid] = bias[tid];
  __syncthreads();

  const int idx = blockIdx.x * 256 + tid;       // 0 .. 131071
  const int b = idx >> 14;
  const int t = idx & (T_LEN - 1);
  const float* xb = x + (size_t)b * 256 * T_LEN + t;

  float acc[32];
  #pragma unroll
  for (int o = 0; o < 32; o++) acc[o] = B[o];
  #pragma unroll 4
  for (int c = 0; c < 256; c++) {
    float v = xb[(size_t)c * T_LEN];
    #pragma unroll
    for (int o4 = 0; o4 < 8; o4++) {
      float4 ww = W[c][o4];
      acc[o4*4+0] += ww.x * v; acc[o4*4+1] += ww.y * v;
      acc[o4*4+2] += ww.z * v; acc[o4*4+3] += ww.w * v;
    }
  }
  #pragma unroll
  for (int j = 0; j < 8; j++) {
    size_t p = ((size_t)(b * 8 + j) << 14) + t;
    h[p]    = make_float4(acc[j*4+0], acc[j*4+1], acc[j*4+2], acc[j*4+3]);
    skip[p] = make_float4(0.f, 0.f, 0.f, 0.f);
  }
}

// ---------------- one residual layer (lane-pair split) ----------------
__global__ __launch_bounds__(256, 2) void layer_k(
    const float4* __restrict__ hin, float4* __restrict__ hout, float4* __restrict__ skip,
    const float* __restrict__ cw, const float* __restrict__ cb,
    const float* __restrict__ gw, const float* __restrict__ gb,
    const float* __restrict__ rw, const float* __restrict__ rb,
    const float* __restrict__ sw, const float* __restrict__ sb, int d)
{
  __shared__ float4 WCG[32][32];  // [ic][pos] = (wc0, wc1, wg0, wg1), pos interleaved
  __shared__ float2 WRS[32][32];  // [ic][pos] = (wr, ws), pos interleaved
  __shared__ float BC[32], BG[32], BR[32], BS[32];
  const int tid = threadIdx.x;
  // staging: channel o stored at interleaved position ((o&15)<<1)|(o>>4)
  for (int i = tid; i < 1024; i += 256) {
    int o = i & 31, ic = i >> 5;
    int pos = ((o & 15) << 1) | (o >> 4);
    int q = (o * 32 + ic) * 2;
    WCG[ic][pos] = make_float4(cw[q], cw[q+1], gw[q], gw[q+1]);
    WRS[ic][pos] = make_float2(rw[o*32+ic], sw[o*32+ic]);
  }
  if (tid < 32) { BC[tid]=cb[tid]; BG[tid]=gb[tid]; BR[tid]=rb[tid]; BS[tid]=sb[tid]; }
  __syncthreads();

  const int idx  = blockIdx.x * 256 + tid;   // 0 .. 262143
  const int half = idx & 1;                  // which 16 output channels
  const int tt   = idx >> 1;                 // 0 .. 131071
  const int b = tt >> 14;
  const int t = tt & (T_LEN - 1);
  const int ob = half << 4;                  // output channel base (0 or 16)
  const size_t base = ((size_t)b * 8 << 14) + t;   // + j*T_LEN

  float ht[32], htd[32];
  #pragma unroll
  for (int j = 0; j < 8; j++) {
    float4 v = hin[base + ((size_t)j << 14)];
    ht[j*4+0]=v.x; ht[j*4+1]=v.y; ht[j*4+2]=v.z; ht[j*4+3]=v.w;
  }
  if (t >= d) {
    #pragma unroll
    for (int j = 0; j < 8; j++) {
      float4 v = hin[base + ((size_t)j << 14) - (size_t)d];
      htd[j*4+0]=v.x; htd[j*4+1]=v.y; htd[j*4+2]=v.z; htd[j*4+3]=v.w;
    }
  } else {
    #pragma unroll
    for (int j = 0; j < 32; j++) htd[j] = 0.f;
  }

  // conv + gate: 16 outputs per thread. Read pos = (o<<1)|half -> channel ob+o.
  float p[16], g[16];
  #pragma unroll
  for (int o = 0; o < 16; o++) { p[o] = BC[ob+o]; g[o] = BG[ob+o]; }
  #pragma unroll
  for (int ic = 0; ic < 32; ic++) {
    float a0 = htd[ic], a1 = ht[ic];
    #pragma unroll
    for (int o = 0; o < 16; o++) {
      float4 w = WCG[ic][(o << 1) | half];
      p[o] += w.x * a0 + w.y * a1;
      g[o] += w.z * a0 + w.w * a1;
    }
  }

  // compact residual inputs NOW so ht[32]/htd[32] die (live-set control)
  float hsel[16];
  #pragma unroll
  for (int o = 0; o < 16; o++) hsel[o] = half ? ht[16 + o] : ht[o];

  float av[16];
  #pragma unroll
  for (int o = 0; o < 16; o++) av[o] = fast_tanh(p[o]) * fast_sig(g[o]);

  // exchange: partner lane (same t, other half) is lane^1
  float aa[32];
  #pragma unroll
  for (int o = 0; o < 16; o++) {
    float ao = __shfl_xor(av[o], 1, 64);
    aa[o]      = half ? ao    : av[o];
    aa[16 + o] = half ? av[o] : ao;
  }

  // prefetch skip (consumed at the very end; latency hidden under res/skip matmul)
  float4 sv[4];
  #pragma unroll
  for (int j = 0; j < 4; j++) sv[j] = skip[base + ((size_t)(half*4 + j) << 14)];

  float hn[16], sk[16];
  #pragma unroll
  for (int o = 0; o < 16; o++) {
    hn[o] = hsel[o] + BR[ob+o];
    sk[o] = BS[ob+o];
  }
  #pragma unroll
  for (int ic = 0; ic < 32; ic++) {
    float v = aa[ic];
    #pragma unroll
    for (int o = 0; o < 16; o++) {
      float2 w = WRS[ic][(o << 1) | half];
      hn[o] += w.x * v;
      sk[o] += w.y * v;
    }
  }

  #pragma unroll
  for (int j = 0; j < 4; j++) {
    size_t p4 = base + ((size_t)(half*4 + j) << 14);
    hout[p4] = make_float4(hn[j*4+0], hn[j*4+1], hn[j*4+2], hn[j*4+3]);
    float4 s = sv[j];
    s.x += sk[j*4+0]; s.y += sk[j*4+1]; s.z += sk[j*4+2]; s.w += sk[j*4+3];
    skip[p4] = s;
  }
}

// ---------------- out: relu(W1 @ skip + b1) -> W2 @ . + b2 ----------------
__global__ __launch_bounds__(256, 2) void out_k(
    const float4* __restrict__ skip,
    const float* __restrict__ w1, const float* __restrict__ b1,
    const float* __restrict__ w2, const float* __restrict__ b2,
    float* __restrict__ out)
{
  __shared__ float4 W1[32][8];    // [ic][o4]
  __shared__ float4 W2[32][64];   // [ic][o4]
  __shared__ float B1[32];
  __shared__ float B2[256];
  const int tid = threadIdx.x;
  {
    int ic = tid >> 3, o4 = tid & 7;
    W1[ic][o4] = make_float4(w1[(o4*4+0)*32+ic], w1[(o4*4+1)*32+ic],
                             w1[(o4*4+2)*32+ic], w1[(o4*4+3)*32+ic]);
  }
  for (int e = tid; e < 2048; e += 256) {
    int ic = e >> 6, o4 = e & 63;
    W2[ic][o4] = make_float4(w2[(o4*4+0)*32+ic], w2[(o4*4+1)*32+ic],
                             w2[(o4*4+2)*32+ic], w2[(o4*4+3)*32+ic]);
  }
  B2[tid & 255] = b2[tid & 255];
  if (tid < 32) B1[tid] = b1[tid];
  __syncthreads();

  const int idx = blockIdx.x * 256 + tid;
  const int b = idx >> 14;
  const int t = idx & (T_LEN - 1);
  const size_t base = ((size_t)b * 8 << 14) + t;

  float sk[32];
  #pragma unroll
  for (int j = 0; j < 8; j++) {
    float4 v = skip[base + ((size_t)j << 14)];
    sk[j*4+0]=v.x; sk[j*4+1]=v.y; sk[j*4+2]=v.z; sk[j*4+3]=v.w;
  }

  float r[32];
  #pragma unroll
  for (int o = 0; o < 32; o++) r[o] = B1[o];
  #pragma unroll
  for (int ic = 0; ic < 32; ic++) {
    float v = sk[ic];
    #pragma unroll
    for (int o4 = 0; o4 < 8; o4++) {
      float4 w = W1[ic][o4];
      r[o4*4+0] += w.x * v; r[o4*4+1] += w.y * v;
      r[o4*4+2] += w.z * v; r[o4*4+3] += w.w * v;
    }
  }
  #pragma unroll
  for (int o = 0; o < 32; o++) r[o] = fmaxf(r[o], 0.f);

  float* ob = out + (size_t)b * 256 * T_LEN + t;
  #pragma unroll 2
  for (int o4 = 0; o4 < 64; o4++) {
    float a0 = B2[o4*4+0], a1 = B2[o4*4+1], a2 = B2[o4*4+2], a3 = B2[o4*4+3];
    #pragma unroll
    for (int ic = 0; ic < 32; ic++) {
      float4 w = W2[ic][o4];
      float v = r[ic];
      a0 += w.x * v; a1 += w.y * v; a2 += w.z * v; a3 += w.w * v;
    }
    ob[(size_t)(o4*4+0)*T_LEN] = a0;
    ob[(size_t)(o4*4+1)*T_LEN] = a1;
    ob[(size_t)(o4*4+2)*T_LEN] = a2;
    ob[(size_t)(o4*4+3)*T_LEN] = a3;
  }
}

extern "C" void kernel_launch(void* const* d_in, const int* in_sizes, int n_in,
                              void* d_out, int out_size, void* d_ws, size_t ws_size,
                              hipStream_t stream)
{
  const float* x    = (const float*)d_in[0];
  const float* in_w = (const float*)d_in[1];
  const float* in_b = (const float*)d_in[2];
  const float* cw   = (const float*)d_in[3];
  const float* cb   = (const float*)d_in[4];
  const float* gw   = (const float*)d_in[5];
  const float* gb   = (const float*)d_in[6];
  const float* rw   = (const float*)d_in[7];
  const float* rb   = (const float*)d_in[8];
  const float* sw   = (const float*)d_in[9];
  const float* sb   = (const float*)d_in[10];
  const float* w1   = (const float*)d_in[11];
  const float* b1   = (const float*)d_in[12];
  const float* w2   = (const float*)d_in[13];
  const float* b2   = (const float*)d_in[14];
  float* out = (float*)d_out;

  // h ping-pong (2 x 16 MB) in d_out scratch (overwritten by out_k); skip in d_ws.
  float4* h0   = (float4*)out;               // 1,048,576 float4s each
  float4* h1   = (float4*)(out + 4194304);
  float4* skip = (float4*)d_ws;

  dim3 blk(256);
  in_k<<<dim3(512), blk, 0, stream>>>(x, in_w, in_b, h0, skip);

  float4* ha = h0;
  float4* hb = h1;
  for (int l = 0; l < 40; l++) {
    int d = 1 << (l % 10);
    layer_k<<<dim3(1024), blk, 0, stream>>>(ha, hb, skip,
        cw + (size_t)l * 2048, cb + l * 32,
        gw + (size_t)l * 2048, gb + l * 32,
        rw + (size_t)l * 1024, rb + l * 32,
        sw + (size_t)l * 1024, sb + l * 32, d);
    float4* tmp = ha; ha = hb; hb = tmp;
  }

  out_k<<<dim3(512), blk, 0, stream>>>(skip, w1, b1, w2, b2, out);
}

// Round 3
// 1212.986 us; speedup vs baseline: 8.6342x; 2.1815x over previous
//
#include <hip/hip_runtime.h>

#define T_LEN 16384

typedef _Float16 f16;
typedef f16 f16x8 __attribute__((ext_vector_type(8)));
typedef float f32x4 __attribute__((ext_vector_type(4)));

__device__ __forceinline__ float fast_exp2(float x) { return __builtin_amdgcn_exp2f(x); }
__device__ __forceinline__ float fast_rcp(float x)  { return __builtin_amdgcn_rcpf(x); }
__device__ __forceinline__ float fast_tanh(float x) {
  return 1.f - 2.f * fast_rcp(1.f + fast_exp2(x * 2.885390081777927f));
}
__device__ __forceinline__ float fast_sig(float x) {
  return fast_rcp(1.f + fast_exp2(-x * 1.4426950408889634f));
}

__device__ __forceinline__ f32x4 mfma16(f16x8 a, f16x8 b, f32x4 c) {
  return __builtin_amdgcn_mfma_f32_16x16x32_f16(a, b, c, 0, 0, 0);
}

// fp32 -> f16 hi/lo split (Ootomo): x ~= hi + lo, |lo| <= 2^-11 |x|.
// A*B ~= Ah*Bh + Ah*Bl + Al*Bh  (dropped Al*Bl term ~2^-22 relative).
struct h2s { f16 hi, lo; };
__device__ __forceinline__ h2s split(float v) {
  h2s r; r.hi = (f16)v; r.lo = (f16)(v - (float)r.hi); return r;
}

// h/skip global layout: float4 index ((b*8 + j) * T_LEN + t), j = channel quad.

// ---------------- input projection 256->32 ----------------
__global__ __launch_bounds__(256, 2) void in_k(
    const float* __restrict__ x, const float* __restrict__ w,
    const float* __restrict__ bias, float4* __restrict__ h, float4* __restrict__ skip)
{
  __shared__ float4 W[256][8];   // [c][o4] = w[(o4*4+j)*256 + c]
  __shared__ float B[32];
  const int tid = threadIdx.x;
  for (int i = tid; i < 2048; i += 256) {
    int c = i >> 3, o4 = i & 7;
    W[c][o4] = make_float4(w[(o4*4+0)*256 + c], w[(o4*4+1)*256 + c],
                           w[(o4*4+2)*256 + c], w[(o4*4+3)*256 + c]);
  }
  if (tid < 32) B[tid] = bias[tid];
  __syncthreads();

  const int idx = blockIdx.x * 256 + tid;       // 0 .. 131071
  const int b = idx >> 14;
  const int t = idx & (T_LEN - 1);
  const float* xb = x + (size_t)b * 256 * T_LEN + t;

  float acc[32];
  #pragma unroll
  for (int o = 0; o < 32; o++) acc[o] = B[o];
  #pragma unroll 4
  for (int c = 0; c < 256; c++) {
    float v = xb[(size_t)c * T_LEN];
    #pragma unroll
    for (int o4 = 0; o4 < 8; o4++) {
      float4 ww = W[c][o4];
      acc[o4*4+0] += ww.x * v; acc[o4*4+1] += ww.y * v;
      acc[o4*4+2] += ww.z * v; acc[o4*4+3] += ww.w * v;
    }
  }
  #pragma unroll
  for (int j = 0; j < 8; j++) {
    size_t p = ((size_t)(b * 8 + j) << 14) + t;
    h[p]    = make_float4(acc[j*4+0], acc[j*4+1], acc[j*4+2], acc[j*4+3]);
    skip[p] = make_float4(0.f, 0.f, 0.f, 0.f);
  }
}

// ---------------- one residual layer: MFMA version ----------------
// Per wave: 4 tiles of 16 t-columns. mfma_f32_16x16x32_f16, fragment layouts
// (guide m89-verified): A[m][k]: m=lane&15, k=(lane>>4)*8+i
//                       B[k][n]: n=lane&15, k=(lane>>4)*8+i
//                       C[m][n]: n=lane&15, m=(lane>>4)*4+reg
// Weights (6 logical 32x32 matrices -> 2 m-tiles each, hi/lo) = 96 VGPR,
// built once per wave per layer. No LDS; the a(C-layout)->B-layout
// redistribution between GEMM1 and GEMM2 is 16 __shfl (ds_bpermute).
// Per tile: 36 MFMAs; 8 float4 loads; 4 float4 stores. 3072 VALU FMAs/thread
// of the old version move to the matrix pipe; LDS weight reads (1024
// instrs/thread, the round-2 bottleneck) vanish.
__global__ __launch_bounds__(256, 1) void layer_k(
    const float4* __restrict__ hin, float4* __restrict__ hout, float4* __restrict__ skip,
    const float* __restrict__ cw, const float* __restrict__ cb,
    const float* __restrict__ gw, const float* __restrict__ gb,
    const float* __restrict__ rw, const float* __restrict__ rb,
    const float* __restrict__ sw, const float* __restrict__ sb, int d)
{
  const int tid  = threadIdx.x;
  const int lane = tid & 63;
  const int g    = lane >> 4;     // 16-lane group: k-group for A/B, row-group for C
  const int m16  = lane & 15;     // A row (out-ch), B/C col (t)

  // ---------- weight A-fragments, held in VGPRs for the whole layer ----------
  f16x8 wch[2][2], wcl[2][2], wgh[2][2], wgl[2][2];   // [mtile][tap]
  f16x8 wrh[2], wrl[2], wsh[2], wsl[2];
  f32x4 cbv[2], gbv[2], rbv[2], sbv[2];
  #pragma unroll
  for (int mt = 0; mt < 2; mt++) {
    const int o = mt*16 + m16;
    const float4* cp = (const float4*)&cw[(o*32 + 8*g)*2];  // 16 floats: (tap0,tap1) x 8 ic
    const float4* gp = (const float4*)&gw[(o*32 + 8*g)*2];
    float4 c0=cp[0], c1=cp[1], c2=cp[2], c3=cp[3];
    float4 g0=gp[0], g1=gp[1], g2=gp[2], g3=gp[3];
    float4 r0 = *(const float4*)&rw[o*32 + 8*g];
    float4 r1 = *(const float4*)&rw[o*32 + 8*g + 4];
    float4 s0 = *(const float4*)&sw[o*32 + 8*g];
    float4 s1 = *(const float4*)&sw[o*32 + 8*g + 4];
    float cc[16] = {c0.x,c0.y,c0.z,c0.w, c1.x,c1.y,c1.z,c1.w,
                    c2.x,c2.y,c2.z,c2.w, c3.x,c3.y,c3.z,c3.w};
    float gg[16] = {g0.x,g0.y,g0.z,g0.w, g1.x,g1.y,g1.z,g1.w,
                    g2.x,g2.y,g2.z,g2.w, g3.x,g3.y,g3.z,g3.w};
    float rr[8] = {r0.x,r0.y,r0.z,r0.w, r1.x,r1.y,r1.z,r1.w};
    float ss[8] = {s0.x,s0.y,s0.z,s0.w, s1.x,s1.y,s1.z,s1.w};
    #pragma unroll
    for (int i = 0; i < 8; i++) {
      h2s t0 = split(cc[2*i+0]); wch[mt][0][i]=t0.hi; wcl[mt][0][i]=t0.lo;
      h2s t1 = split(cc[2*i+1]); wch[mt][1][i]=t1.hi; wcl[mt][1][i]=t1.lo;
      h2s u0 = split(gg[2*i+0]); wgh[mt][0][i]=u0.hi; wgl[mt][0][i]=u0.lo;
      h2s u1 = split(gg[2*i+1]); wgh[mt][1][i]=u1.hi; wgl[mt][1][i]=u1.lo;
      h2s vr = split(rr[i]);     wrh[mt][i]=vr.hi;    wrl[mt][i]=vr.lo;
      h2s vs = split(ss[i]);     wsh[mt][i]=vs.hi;    wsl[mt][i]=vs.lo;
    }
    cbv[mt] = *(const f32x4*)&cb[mt*16 + 4*g];
    gbv[mt] = *(const f32x4*)&gb[mt*16 + 4*g];
    rbv[mt] = *(const f32x4*)&rb[mt*16 + 4*g];
    sbv[mt] = *(const f32x4*)&sb[mt*16 + 4*g];
  }

  const int wid   = (blockIdx.x << 2) | (tid >> 6);   // 0..2047
  const int tile0 = wid << 2;                          // 4 tiles per wave

  // B-stream double buffer: [buf][0,1]=h[t] quads 2g,2g+1; [2,3]=h[t-d]
  float4 Bst[2][4];
  {
    const int b = tile0 >> 10;
    const int tcol = ((tile0 << 4) & (T_LEN-1)) + m16;
    const size_t cbase = ((size_t)b << 17) + (size_t)tcol;
    Bst[0][0] = hin[cbase + ((size_t)(2*g)   << 14)];
    Bst[0][1] = hin[cbase + ((size_t)(2*g+1) << 14)];
    float4 z = make_float4(0.f,0.f,0.f,0.f);
    Bst[0][2] = z; Bst[0][3] = z;
    if (tcol >= d) {
      Bst[0][2] = hin[cbase - (size_t)d + ((size_t)(2*g)   << 14)];
      Bst[0][3] = hin[cbase - (size_t)d + ((size_t)(2*g+1) << 14)];
    }
  }

  #pragma unroll
  for (int k = 0; k < 4; k++) {
    const int tile = tile0 + k;
    const int b = tile >> 10;
    const int tcol = ((tile << 4) & (T_LEN-1)) + m16;
    const size_t cbase = ((size_t)b << 17) + (size_t)tcol;
    const int cur = k & 1, nxt = cur ^ 1;

    // early-issue epilogue inputs (consumed after ~30 MFMAs)
    float4 hr0 = hin[cbase  + ((size_t)g     << 14)];   // quad g   (mt0 C rows)
    float4 hr1 = hin[cbase  + ((size_t)(4+g) << 14)];   // quad 4+g (mt1 C rows)
    float4 sv0 = skip[cbase + ((size_t)g     << 14)];
    float4 sv1 = skip[cbase + ((size_t)(4+g) << 14)];

    // build B fragments (hi/lo) for h[t] and h[t-d]
    f16x8 bth, btl, bdh, bdl;
    {
      float tv[8] = {Bst[cur][0].x,Bst[cur][0].y,Bst[cur][0].z,Bst[cur][0].w,
                     Bst[cur][1].x,Bst[cur][1].y,Bst[cur][1].z,Bst[cur][1].w};
      float dv[8] = {Bst[cur][2].x,Bst[cur][2].y,Bst[cur][2].z,Bst[cur][2].w,
                     Bst[cur][3].x,Bst[cur][3].y,Bst[cur][3].z,Bst[cur][3].w};
      #pragma unroll
      for (int i = 0; i < 8; i++) {
        h2s a = split(tv[i]); bth[i]=a.hi; btl[i]=a.lo;
        h2s c = split(dv[i]); bdh[i]=c.hi; bdl[i]=c.lo;
      }
    }

    // prefetch next tile's B streams (1-deep)
    if (k < 3) {
      const int tn = tile + 1;
      const int bn = tn >> 10;
      const int tcn = ((tn << 4) & (T_LEN-1)) + m16;
      const size_t cbn = ((size_t)bn << 17) + (size_t)tcn;
      Bst[nxt][0] = hin[cbn + ((size_t)(2*g)   << 14)];
      Bst[nxt][1] = hin[cbn + ((size_t)(2*g+1) << 14)];
      float4 z = make_float4(0.f,0.f,0.f,0.f);
      Bst[nxt][2] = z; Bst[nxt][3] = z;
      if (tcn >= d) {
        Bst[nxt][2] = hin[cbn - (size_t)d + ((size_t)(2*g)   << 14)];
        Bst[nxt][3] = hin[cbn - (size_t)d + ((size_t)(2*g+1) << 14)];
      }
    }

    // GEMM1: p = Wc0*h[t-d] + Wc1*h[t], g = Wg0*h[t-d] + Wg1*h[t]
    f32x4 pa[2], ga[2];
    #pragma unroll
    for (int mt = 0; mt < 2; mt++) {
      f32x4 p = {0.f,0.f,0.f,0.f};
      p = mfma16(wch[mt][0], bdh, p);
      p = mfma16(wcl[mt][0], bdh, p);
      p = mfma16(wch[mt][0], bdl, p);
      p = mfma16(wch[mt][1], bth, p);
      p = mfma16(wcl[mt][1], bth, p);
      p = mfma16(wch[mt][1], btl, p);
      pa[mt] = p;
      f32x4 q = {0.f,0.f,0.f,0.f};
      q = mfma16(wgh[mt][0], bdh, q);
      q = mfma16(wgl[mt][0], bdh, q);
      q = mfma16(wgh[mt][0], bdl, q);
      q = mfma16(wgh[mt][1], bth, q);
      q = mfma16(wgl[mt][1], bth, q);
      q = mfma16(wgh[mt][1], btl, q);
      ga[mt] = q;
    }

    // gated activation on C-layout accumulators
    float av0[4], av1[4];
    #pragma unroll
    for (int r = 0; r < 4; r++) {
      av0[r] = fast_tanh(pa[0][r] + cbv[0][r]) * fast_sig(ga[0][r] + gbv[0][r]);
      av1[r] = fast_tanh(pa[1][r] + cbv[1][r]) * fast_sig(ga[1][r] + gbv[1][r]);
    }

    // redistribute a: C-layout (ch = mt*16+4*src_g+r at lane src_g*16+n)
    //             -> B-layout (lane group g needs ch 8g..8g+7 at col n)
    f16x8 bah, bal;
    #pragma unroll
    for (int i = 0; i < 8; i++) {
      int srcl = (((2*g + (i>>2)) & 3) << 4) | m16;
      float v0 = __shfl(av0[i&3], srcl, 64);
      float v1 = __shfl(av1[i&3], srcl, 64);
      float v = (g >= 2) ? v1 : v0;
      h2s s = split(v); bah[i]=s.hi; bal[i]=s.lo;
    }

    // GEMM2: res & skip
    f32x4 ra[2], sa[2];
    #pragma unroll
    for (int mt = 0; mt < 2; mt++) {
      f32x4 p = {0.f,0.f,0.f,0.f};
      p = mfma16(wrh[mt], bah, p);
      p = mfma16(wrl[mt], bah, p);
      p = mfma16(wrh[mt], bal, p);
      ra[mt] = p;
      f32x4 q = {0.f,0.f,0.f,0.f};
      q = mfma16(wsh[mt], bah, q);
      q = mfma16(wsl[mt], bah, q);
      q = mfma16(wsh[mt], bal, q);
      sa[mt] = q;
    }

    // epilogue: residual add + skip accumulate; C rows mt*16+4g..+3 = quad 4mt+g
    #pragma unroll
    for (int mt = 0; mt < 2; mt++) {
      size_t qidx = cbase + ((size_t)(4*mt + g) << 14);
      float4 hr = (mt == 0) ? hr0 : hr1;
      float4 sv = (mt == 0) ? sv0 : sv1;
      hout[qidx] = make_float4(hr.x + rbv[mt][0] + ra[mt][0],
                               hr.y + rbv[mt][1] + ra[mt][1],
                               hr.z + rbv[mt][2] + ra[mt][2],
                               hr.w + rbv[mt][3] + ra[mt][3]);
      skip[qidx] = make_float4(sv.x + sbv[mt][0] + sa[mt][0],
                               sv.y + sbv[mt][1] + sa[mt][1],
                               sv.z + sbv[mt][2] + sa[mt][2],
                               sv.w + sbv[mt][3] + sa[mt][3]);
    }
  }
}

// ---------------- out: relu(W1 @ skip + b1) -> W2 @ . + b2 ----------------
__global__ __launch_bounds__(256, 2) void out_k(
    const float4* __restrict__ skip,
    const float* __restrict__ w1, const float* __restrict__ b1,
    const float* __restrict__ w2, const float* __restrict__ b2,
    float* __restrict__ out)
{
  __shared__ float4 W1[32][8];    // [ic][o4]
  __shared__ float4 W2[32][64];   // [ic][o4]
  __shared__ float B1[32];
  __shared__ float B2[256];
  const int tid = threadIdx.x;
  {
    int ic = tid >> 3, o4 = tid & 7;
    W1[ic][o4] = make_float4(w1[(o4*4+0)*32+ic], w1[(o4*4+1)*32+ic],
                             w1[(o4*4+2)*32+ic], w1[(o4*4+3)*32+ic]);
  }
  for (int e = tid; e < 2048; e += 256) {
    int ic = e >> 6, o4 = e & 63;
    W2[ic][o4] = make_float4(w2[(o4*4+0)*32+ic], w2[(o4*4+1)*32+ic],
                             w2[(o4*4+2)*32+ic], w2[(o4*4+3)*32+ic]);
  }
  B2[tid & 255] = b2[tid & 255];
  if (tid < 32) B1[tid] = b1[tid];
  __syncthreads();

  const int idx = blockIdx.x * 256 + tid;
  const int b = idx >> 14;
  const int t = idx & (T_LEN - 1);
  const size_t base = ((size_t)b * 8 << 14) + t;

  float sk[32];
  #pragma unroll
  for (int j = 0; j < 8; j++) {
    float4 v = skip[base + ((size_t)j << 14)];
    sk[j*4+0]=v.x; sk[j*4+1]=v.y; sk[j*4+2]=v.z; sk[j*4+3]=v.w;
  }

  float r[32];
  #pragma unroll
  for (int o = 0; o < 32; o++) r[o] = B1[o];
  #pragma unroll
  for (int ic = 0; ic < 32; ic++) {
    float v = sk[ic];
    #pragma unroll
    for (int o4 = 0; o4 < 8; o4++) {
      float4 w = W1[ic][o4];
      r[o4*4+0] += w.x * v; r[o4*4+1] += w.y * v;
      r[o4*4+2] += w.z * v; r[o4*4+3] += w.w * v;
    }
  }
  #pragma unroll
  for (int o = 0; o < 32; o++) r[o] = fmaxf(r[o], 0.f);

  float* ob = out + (size_t)b * 256 * T_LEN + t;
  #pragma unroll 2
  for (int o4 = 0; o4 < 64; o4++) {
    float a0 = B2[o4*4+0], a1 = B2[o4*4+1], a2 = B2[o4*4+2], a3 = B2[o4*4+3];
    #pragma unroll
    for (int ic = 0; ic < 32; ic++) {
      float4 w = W2[ic][o4];
      float v = r[ic];
      a0 += w.x * v; a1 += w.y * v; a2 += w.z * v; a3 += w.w * v;
    }
    ob[(size_t)(o4*4+0)*T_LEN] = a0;
    ob[(size_t)(o4*4+1)*T_LEN] = a1;
    ob[(size_t)(o4*4+2)*T_LEN] = a2;
    ob[(size_t)(o4*4+3)*T_LEN] = a3;
  }
}

extern "C" void kernel_launch(void* const* d_in, const int* in_sizes, int n_in,
                              void* d_out, int out_size, void* d_ws, size_t ws_size,
                              hipStream_t stream)
{
  const float* x    = (const float*)d_in[0];
  const float* in_w = (const float*)d_in[1];
  const float* in_b = (const float*)d_in[2];
  const float* cw   = (const float*)d_in[3];
  const float* cb   = (const float*)d_in[4];
  const float* gw   = (const float*)d_in[5];
  const float* gb   = (const float*)d_in[6];
  const float* rw   = (const float*)d_in[7];
  const float* rb   = (const float*)d_in[8];
  const float* sw   = (const float*)d_in[9];
  const float* sb   = (const float*)d_in[10];
  const float* w1   = (const float*)d_in[11];
  const float* b1   = (const float*)d_in[12];
  const float* w2   = (const float*)d_in[13];
  const float* b2   = (const float*)d_in[14];
  float* out = (float*)d_out;

  // h ping-pong (2 x 16 MB) in d_out scratch (overwritten by out_k); skip in d_ws.
  float4* h0   = (float4*)out;               // 1,048,576 float4s each
  float4* h1   = (float4*)(out + 4194304);
  float4* skip = (float4*)d_ws;

  dim3 blk(256);
  in_k<<<dim3(512), blk, 0, stream>>>(x, in_w, in_b, h0, skip);

  float4* ha = h0;
  float4* hb = h1;
  for (int l = 0; l < 40; l++) {
    int d = 1 << (l % 10);
    layer_k<<<dim3(512), blk, 0, stream>>>(ha, hb, skip,
        cw + (size_t)l * 2048, cb + l * 32,
        gw + (size_t)l * 2048, gb + l * 32,
        rw + (size_t)l * 1024, rb + l * 32,
        sw + (size_t)l * 1024, sb + l * 32, d);
    float4* tmp = ha; ha = hb; hb = tmp;
  }

  out_k<<<dim3(512), blk, 0, stream>>>(skip, w1, b1, w2, b2, out);
}

// Round 4
// 1175.781 us; speedup vs baseline: 8.9074x; 1.0316x over previous
//
#include <hip/hip_runtime.h>

#define T_LEN 16384

typedef _Float16 f16;
typedef f16 f16x8 __attribute__((ext_vector_type(8)));
typedef float f32x4 __attribute__((ext_vector_type(4)));

__device__ __forceinline__ float fast_exp2(float x) { return __builtin_amdgcn_exp2f(x); }
__device__ __forceinline__ float fast_rcp(float x)  { return __builtin_amdgcn_rcpf(x); }
__device__ __forceinline__ float fast_tanh(float x) {
  return 1.f - 2.f * fast_rcp(1.f + fast_exp2(x * 2.885390081777927f));
}
__device__ __forceinline__ float fast_sig(float x) {
  return fast_rcp(1.f + fast_exp2(-x * 1.4426950408889634f));
}

__device__ __forceinline__ f32x4 mfma16(f16x8 a, f16x8 b, f32x4 c) {
  return __builtin_amdgcn_mfma_f32_16x16x32_f16(a, b, c, 0, 0, 0);
}

// fp32 -> f16 hi/lo split (Ootomo): x ~= hi + lo, |lo| <= 2^-11 |x|.
// A*B ~= Ah*Bh + Ah*Bl + Al*Bh  (dropped Al*Bl term ~2^-22 relative).
struct h2s { f16 hi, lo; };
__device__ __forceinline__ h2s split(float v) {
  h2s r; r.hi = (f16)v; r.lo = (f16)(v - (float)r.hi); return r;
}

// h/skip global layout: float4 index ((b*8 + j) * T_LEN + t), j = channel quad.
// MFMA fragment conventions (m89-verified, validated by round-3 refcheck):
//   A[m][k]: m=lane&15, k=(lane>>4)*8+i
//   B[k][n]: n=lane&15, k=(lane>>4)*8+i
//   C[m][n]: n=lane&15, m=(lane>>4)*4+reg

// ---------------- input projection 256->32 (MFMA, K=256) ----------------
// Per wave: 4 tiles of 16 t-cols. A = in_w (2 m-tiles x 8 k-tiles, hi/lo in
// 128 VGPR, loaded once). B streamed from x: 64 coalesced scalar loads per
// lane per tile (16KB in flight per wave -> HBM latency covered at 8 waves/CU).
// Round-3 in_k was LDS-service bound (~2048 ds_read_b128/thread ~= 62us);
// this version has zero LDS. Floor: 134 MB fetch / 6.3 TB/s ~= 21 us.
__global__ __launch_bounds__(256, 1) void in_k(
    const float* __restrict__ x, const float* __restrict__ w,
    const float* __restrict__ bias, float4* __restrict__ h, float4* __restrict__ skip)
{
  const int tid  = threadIdx.x;
  const int lane = tid & 63;
  const int g    = lane >> 4;
  const int m16  = lane & 15;

  f16x8 wh[2][8], wl[2][8];
  #pragma unroll
  for (int mt = 0; mt < 2; mt++) {
    #pragma unroll
    for (int kt = 0; kt < 8; kt++) {
      const float4* wp = (const float4*)&w[(mt*16 + m16)*256 + kt*32 + 8*g];
      float4 w0 = wp[0], w1 = wp[1];
      float ww[8] = {w0.x,w0.y,w0.z,w0.w, w1.x,w1.y,w1.z,w1.w};
      #pragma unroll
      for (int i = 0; i < 8; i++) {
        h2s s = split(ww[i]); wh[mt][kt][i] = s.hi; wl[mt][kt][i] = s.lo;
      }
    }
  }
  f32x4 bv[2];
  bv[0] = *(const f32x4*)&bias[4*g];
  bv[1] = *(const f32x4*)&bias[16 + 4*g];

  const int wid   = (blockIdx.x << 2) | (tid >> 6);   // 0..2047
  const int tile0 = wid << 2;

  #pragma unroll
  for (int k = 0; k < 4; k++) {
    const int tile = tile0 + k;
    const int b    = tile >> 10;
    const int tcol = ((tile << 4) & (T_LEN - 1)) + m16;
    const float* xb = x + (size_t)b * 256 * T_LEN + tcol;

    float tv[8][8];
    #pragma unroll
    for (int kt = 0; kt < 8; kt++)
      #pragma unroll
      for (int i = 0; i < 8; i++)
        tv[kt][i] = xb[(size_t)(kt*32 + 8*g + i) * T_LEN];

    f32x4 acc[2] = {bv[0], bv[1]};
    #pragma unroll
    for (int kt = 0; kt < 8; kt++) {
      f16x8 bh, bl;
      #pragma unroll
      for (int i = 0; i < 8; i++) { h2s s = split(tv[kt][i]); bh[i]=s.hi; bl[i]=s.lo; }
      #pragma unroll
      for (int mt = 0; mt < 2; mt++) {
        acc[mt] = mfma16(wh[mt][kt], bh, acc[mt]);
        acc[mt] = mfma16(wl[mt][kt], bh, acc[mt]);
        acc[mt] = mfma16(wh[mt][kt], bl, acc[mt]);
      }
    }

    const size_t cbase = ((size_t)b << 17) + (size_t)tcol;
    const float4 z = make_float4(0.f, 0.f, 0.f, 0.f);
    #pragma unroll
    for (int mt = 0; mt < 2; mt++) {
      size_t qidx = cbase + ((size_t)(4*mt + g) << 14);
      h[qidx]    = make_float4(acc[mt][0], acc[mt][1], acc[mt][2], acc[mt][3]);
      skip[qidx] = z;
    }
  }
}

// ---------------- one residual layer: MFMA version ----------------
// Unchanged from round 3 except: XCD-aware block swizzle. 512 blocks / 8 XCDs
// -> each XCD gets 64 consecutive swizzled blocks = one full batch's t-range
// (hin chunk 2.1 MB < 4 MB L2), so the h[t-d] halo stream and skip RMW become
// L2 hits instead of HBM re-fetches.
__global__ __launch_bounds__(256, 1) void layer_k(
    const float4* __restrict__ hin, float4* __restrict__ hout, float4* __restrict__ skip,
    const float* __restrict__ cw, const float* __restrict__ cb,
    const float* __restrict__ gw, const float* __restrict__ gb,
    const float* __restrict__ rw, const float* __restrict__ rb,
    const float* __restrict__ sw, const float* __restrict__ sb, int d)
{
  const int tid  = threadIdx.x;
  const int lane = tid & 63;
  const int g    = lane >> 4;     // 16-lane group: k-group for A/B, row-group for C
  const int m16  = lane & 15;     // A row (out-ch), B/C col (t)

  // ---------- weight A-fragments, held in VGPRs for the whole layer ----------
  f16x8 wch[2][2], wcl[2][2], wgh[2][2], wgl[2][2];   // [mtile][tap]
  f16x8 wrh[2], wrl[2], wsh[2], wsl[2];
  f32x4 cbv[2], gbv[2], rbv[2], sbv[2];
  #pragma unroll
  for (int mt = 0; mt < 2; mt++) {
    const int o = mt*16 + m16;
    const float4* cp = (const float4*)&cw[(o*32 + 8*g)*2];  // 16 floats: (tap0,tap1) x 8 ic
    const float4* gp = (const float4*)&gw[(o*32 + 8*g)*2];
    float4 c0=cp[0], c1=cp[1], c2=cp[2], c3=cp[3];
    float4 g0=gp[0], g1=gp[1], g2=gp[2], g3=gp[3];
    float4 r0 = *(const float4*)&rw[o*32 + 8*g];
    float4 r1 = *(const float4*)&rw[o*32 + 8*g + 4];
    float4 s0 = *(const float4*)&sw[o*32 + 8*g];
    float4 s1 = *(const float4*)&sw[o*32 + 8*g + 4];
    float cc[16] = {c0.x,c0.y,c0.z,c0.w, c1.x,c1.y,c1.z,c1.w,
                    c2.x,c2.y,c2.z,c2.w, c3.x,c3.y,c3.z,c3.w};
    float gg[16] = {g0.x,g0.y,g0.z,g0.w, g1.x,g1.y,g1.z,g1.w,
                    g2.x,g2.y,g2.z,g2.w, g3.x,g3.y,g3.z,g3.w};
    float rr[8] = {r0.x,r0.y,r0.z,r0.w, r1.x,r1.y,r1.z,r1.w};
    float ss[8] = {s0.x,s0.y,s0.z,s0.w, s1.x,s1.y,s1.z,s1.w};
    #pragma unroll
    for (int i = 0; i < 8; i++) {
      h2s t0 = split(cc[2*i+0]); wch[mt][0][i]=t0.hi; wcl[mt][0][i]=t0.lo;
      h2s t1 = split(cc[2*i+1]); wch[mt][1][i]=t1.hi; wcl[mt][1][i]=t1.lo;
      h2s u0 = split(gg[2*i+0]); wgh[mt][0][i]=u0.hi; wgl[mt][0][i]=u0.lo;
      h2s u1 = split(gg[2*i+1]); wgh[mt][1][i]=u1.hi; wgl[mt][1][i]=u1.lo;
      h2s vr = split(rr[i]);     wrh[mt][i]=vr.hi;    wrl[mt][i]=vr.lo;
      h2s vs = split(ss[i]);     wsh[mt][i]=vs.hi;    wsl[mt][i]=vs.lo;
    }
    cbv[mt] = *(const f32x4*)&cb[mt*16 + 4*g];
    gbv[mt] = *(const f32x4*)&gb[mt*16 + 4*g];
    rbv[mt] = *(const f32x4*)&rb[mt*16 + 4*g];
    sbv[mt] = *(const f32x4*)&sb[mt*16 + 4*g];
  }

  // XCD swizzle: 512 blocks, bid%8 = XCD -> give each XCD 64 consecutive chunks
  const int bid = blockIdx.x;
  const int swz = ((bid & 7) << 6) | (bid >> 3);
  const int wid   = (swz << 2) | (tid >> 6);          // 0..2047
  const int tile0 = wid << 2;                          // 4 tiles per wave

  // B-stream double buffer: [buf][0,1]=h[t] quads 2g,2g+1; [2,3]=h[t-d]
  float4 Bst[2][4];
  {
    const int b = tile0 >> 10;
    const int tcol = ((tile0 << 4) & (T_LEN-1)) + m16;
    const size_t cbase = ((size_t)b << 17) + (size_t)tcol;
    Bst[0][0] = hin[cbase + ((size_t)(2*g)   << 14)];
    Bst[0][1] = hin[cbase + ((size_t)(2*g+1) << 14)];
    float4 z = make_float4(0.f,0.f,0.f,0.f);
    Bst[0][2] = z; Bst[0][3] = z;
    if (tcol >= d) {
      Bst[0][2] = hin[cbase - (size_t)d + ((size_t)(2*g)   << 14)];
      Bst[0][3] = hin[cbase - (size_t)d + ((size_t)(2*g+1) << 14)];
    }
  }

  #pragma unroll
  for (int k = 0; k < 4; k++) {
    const int tile = tile0 + k;
    const int b = tile >> 10;
    const int tcol = ((tile << 4) & (T_LEN-1)) + m16;
    const size_t cbase = ((size_t)b << 17) + (size_t)tcol;
    const int cur = k & 1, nxt = cur ^ 1;

    // early-issue epilogue inputs (consumed after ~30 MFMAs)
    float4 hr0 = hin[cbase  + ((size_t)g     << 14)];   // quad g   (mt0 C rows)
    float4 hr1 = hin[cbase  + ((size_t)(4+g) << 14)];   // quad 4+g (mt1 C rows)
    float4 sv0 = skip[cbase + ((size_t)g     << 14)];
    float4 sv1 = skip[cbase + ((size_t)(4+g) << 14)];

    // build B fragments (hi/lo) for h[t] and h[t-d]
    f16x8 bth, btl, bdh, bdl;
    {
      float tv[8] = {Bst[cur][0].x,Bst[cur][0].y,Bst[cur][0].z,Bst[cur][0].w,
                     Bst[cur][1].x,Bst[cur][1].y,Bst[cur][1].z,Bst[cur][1].w};
      float dv[8] = {Bst[cur][2].x,Bst[cur][2].y,Bst[cur][2].z,Bst[cur][2].w,
                     Bst[cur][3].x,Bst[cur][3].y,Bst[cur][3].z,Bst[cur][3].w};
      #pragma unroll
      for (int i = 0; i < 8; i++) {
        h2s a = split(tv[i]); bth[i]=a.hi; btl[i]=a.lo;
        h2s c = split(dv[i]); bdh[i]=c.hi; bdl[i]=c.lo;
      }
    }

    // prefetch next tile's B streams (1-deep)
    if (k < 3) {
      const int tn = tile + 1;
      const int bn = tn >> 10;
      const int tcn = ((tn << 4) & (T_LEN-1)) + m16;
      const size_t cbn = ((size_t)bn << 17) + (size_t)tcn;
      Bst[nxt][0] = hin[cbn + ((size_t)(2*g)   << 14)];
      Bst[nxt][1] = hin[cbn + ((size_t)(2*g+1) << 14)];
      float4 z = make_float4(0.f,0.f,0.f,0.f);
      Bst[nxt][2] = z; Bst[nxt][3] = z;
      if (tcn >= d) {
        Bst[nxt][2] = hin[cbn - (size_t)d + ((size_t)(2*g)   << 14)];
        Bst[nxt][3] = hin[cbn - (size_t)d + ((size_t)(2*g+1) << 14)];
      }
    }

    // GEMM1: p = Wc0*h[t-d] + Wc1*h[t], g = Wg0*h[t-d] + Wg1*h[t]
    f32x4 pa[2], ga[2];
    #pragma unroll
    for (int mt = 0; mt < 2; mt++) {
      f32x4 p = {0.f,0.f,0.f,0.f};
      p = mfma16(wch[mt][0], bdh, p);
      p = mfma16(wcl[mt][0], bdh, p);
      p = mfma16(wch[mt][0], bdl, p);
      p = mfma16(wch[mt][1], bth, p);
      p = mfma16(wcl[mt][1], bth, p);
      p = mfma16(wch[mt][1], btl, p);
      pa[mt] = p;
      f32x4 q = {0.f,0.f,0.f,0.f};
      q = mfma16(wgh[mt][0], bdh, q);
      q = mfma16(wgl[mt][0], bdh, q);
      q = mfma16(wgh[mt][0], bdl, q);
      q = mfma16(wgh[mt][1], bth, q);
      q = mfma16(wgl[mt][1], bth, q);
      q = mfma16(wgh[mt][1], btl, q);
      ga[mt] = q;
    }

    // gated activation on C-layout accumulators
    float av0[4], av1[4];
    #pragma unroll
    for (int r = 0; r < 4; r++) {
      av0[r] = fast_tanh(pa[0][r] + cbv[0][r]) * fast_sig(ga[0][r] + gbv[0][r]);
      av1[r] = fast_tanh(pa[1][r] + cbv[1][r]) * fast_sig(ga[1][r] + gbv[1][r]);
    }

    // redistribute a: C-layout (ch = mt*16+4*src_g+r at lane src_g*16+n)
    //             -> B-layout (lane group g needs ch 8g..8g+7 at col n)
    f16x8 bah, bal;
    #pragma unroll
    for (int i = 0; i < 8; i++) {
      int srcl = (((2*g + (i>>2)) & 3) << 4) | m16;
      float v0 = __shfl(av0[i&3], srcl, 64);
      float v1 = __shfl(av1[i&3], srcl, 64);
      float v = (g >= 2) ? v1 : v0;
      h2s s = split(v); bah[i]=s.hi; bal[i]=s.lo;
    }

    // GEMM2: res & skip
    f32x4 ra[2], sa[2];
    #pragma unroll
    for (int mt = 0; mt < 2; mt++) {
      f32x4 p = {0.f,0.f,0.f,0.f};
      p = mfma16(wrh[mt], bah, p);
      p = mfma16(wrl[mt], bah, p);
      p = mfma16(wrh[mt], bal, p);
      ra[mt] = p;
      f32x4 q = {0.f,0.f,0.f,0.f};
      q = mfma16(wsh[mt], bah, q);
      q = mfma16(wsl[mt], bah, q);
      q = mfma16(wsh[mt], bal, q);
      sa[mt] = q;
    }

    // epilogue: residual add + skip accumulate; C rows mt*16+4g..+3 = quad 4mt+g
    #pragma unroll
    for (int mt = 0; mt < 2; mt++) {
      size_t qidx = cbase + ((size_t)(4*mt + g) << 14);
      float4 hr = (mt == 0) ? hr0 : hr1;
      float4 sv = (mt == 0) ? sv0 : sv1;
      hout[qidx] = make_float4(hr.x + rbv[mt][0] + ra[mt][0],
                               hr.y + rbv[mt][1] + ra[mt][1],
                               hr.z + rbv[mt][2] + ra[mt][2],
                               hr.w + rbv[mt][3] + ra[mt][3]);
      skip[qidx] = make_float4(sv.x + sbv[mt][0] + sa[mt][0],
                               sv.y + sbv[mt][1] + sa[mt][1],
                               sv.z + sbv[mt][2] + sa[mt][2],
                               sv.w + sbv[mt][3] + sa[mt][3]);
    }
  }
}

// ---------------- out (MFMA): relu(W1 @ skip + b1) -> W2 @ . + b2 ----------
// Round-3 out_k was LDS-service bound (2048 ds_read_b128/thread of W2
// ~= 70 us). This version holds W1 (2 m-tiles) and W2 (16 m-tiles) as hi/lo
// A-frags in VGPRs (~144), zero LDS. The relu C->B redistribution is the
// layer_k shfl pattern verbatim. Floor: 134 MB write / 6.3 TB/s ~= 21 us.
__global__ __launch_bounds__(256, 1) void out_k(
    const float4* __restrict__ skip,
    const float* __restrict__ w1, const float* __restrict__ b1,
    const float* __restrict__ w2, const float* __restrict__ b2,
    float* __restrict__ out)
{
  const int tid  = threadIdx.x;
  const int lane = tid & 63;
  const int g    = lane >> 4;
  const int m16  = lane & 15;

  f16x8 w1h[2], w1l[2];
  #pragma unroll
  for (int mt = 0; mt < 2; mt++) {
    const float4* wp = (const float4*)&w1[(mt*16 + m16)*32 + 8*g];
    float4 a0 = wp[0], a1 = wp[1];
    float ww[8] = {a0.x,a0.y,a0.z,a0.w, a1.x,a1.y,a1.z,a1.w};
    #pragma unroll
    for (int i = 0; i < 8; i++) { h2s s = split(ww[i]); w1h[mt][i]=s.hi; w1l[mt][i]=s.lo; }
  }
  f16x8 w2h[16], w2l[16];
  #pragma unroll
  for (int mt = 0; mt < 16; mt++) {
    const float4* wp = (const float4*)&w2[(mt*16 + m16)*32 + 8*g];
    float4 a0 = wp[0], a1 = wp[1];
    float ww[8] = {a0.x,a0.y,a0.z,a0.w, a1.x,a1.y,a1.z,a1.w};
    #pragma unroll
    for (int i = 0; i < 8; i++) { h2s s = split(ww[i]); w2h[mt][i]=s.hi; w2l[mt][i]=s.lo; }
  }
  f32x4 b1v[2];
  b1v[0] = *(const f32x4*)&b1[4*g];
  b1v[1] = *(const f32x4*)&b1[16 + 4*g];

  const int wid   = (blockIdx.x << 2) | (tid >> 6);
  const int tile0 = wid << 2;

  #pragma unroll
  for (int k = 0; k < 4; k++) {
    const int tile = tile0 + k;
    const int b    = tile >> 10;
    const int tcol = ((tile << 4) & (T_LEN - 1)) + m16;
    const size_t cbase = ((size_t)b << 17) + (size_t)tcol;

    // B from skip: quads 2g, 2g+1 (channels 8g..8g+7)
    float4 q0 = skip[cbase + ((size_t)(2*g)   << 14)];
    float4 q1 = skip[cbase + ((size_t)(2*g+1) << 14)];
    float sv[8] = {q0.x,q0.y,q0.z,q0.w, q1.x,q1.y,q1.z,q1.w};
    f16x8 bh, bl;
    #pragma unroll
    for (int i = 0; i < 8; i++) { h2s s = split(sv[i]); bh[i]=s.hi; bl[i]=s.lo; }

    // GEMM1 + bias + relu (C layout: ch = mt*16+4g+r, col = m16)
    f32x4 c0 = b1v[0], c1 = b1v[1];
    c0 = mfma16(w1h[0], bh, c0); c0 = mfma16(w1l[0], bh, c0); c0 = mfma16(w1h[0], bl, c0);
    c1 = mfma16(w1h[1], bh, c1); c1 = mfma16(w1l[1], bh, c1); c1 = mfma16(w1h[1], bl, c1);
    float r0[4], r1[4];
    #pragma unroll
    for (int r = 0; r < 4; r++) { r0[r] = fmaxf(c0[r], 0.f); r1[r] = fmaxf(c1[r], 0.f); }

    // redistribute relu(C) -> B layout (layer_k pattern verbatim)
    f16x8 rh, rl;
    #pragma unroll
    for (int i = 0; i < 8; i++) {
      int srcl = (((2*g + (i>>2)) & 3) << 4) | m16;
      float v0 = __shfl(r0[i&3], srcl, 64);
      float v1 = __shfl(r1[i&3], srcl, 64);
      float v = (g >= 2) ? v1 : v0;
      h2s s = split(v); rh[i]=s.hi; rl[i]=s.lo;
    }

    // GEMM2: 16 m-tiles of 16 out-channels; store each immediately
    float* ob = out + (size_t)b * 256 * T_LEN + tcol;
    #pragma unroll
    for (int mt = 0; mt < 16; mt++) {
      f32x4 c = *(const f32x4*)&b2[mt*16 + 4*g];
      c = mfma16(w2h[mt], rh, c);
      c = mfma16(w2l[mt], rh, c);
      c = mfma16(w2h[mt], rl, c);
      #pragma unroll
      for (int r = 0; r < 4; r++)
        ob[(size_t)(mt*16 + 4*g + r) * T_LEN] = c[r];
    }
  }
}

extern "C" void kernel_launch(void* const* d_in, const int* in_sizes, int n_in,
                              void* d_out, int out_size, void* d_ws, size_t ws_size,
                              hipStream_t stream)
{
  const float* x    = (const float*)d_in[0];
  const float* in_w = (const float*)d_in[1];
  const float* in_b = (const float*)d_in[2];
  const float* cw   = (const float*)d_in[3];
  const float* cb   = (const float*)d_in[4];
  const float* gw   = (const float*)d_in[5];
  const float* gb   = (const float*)d_in[6];
  const float* rw   = (const float*)d_in[7];
  const float* rb   = (const float*)d_in[8];
  const float* sw   = (const float*)d_in[9];
  const float* sb   = (const float*)d_in[10];
  const float* w1   = (const float*)d_in[11];
  const float* b1   = (const float*)d_in[12];
  const float* w2   = (const float*)d_in[13];
  const float* b2   = (const float*)d_in[14];
  float* out = (float*)d_out;

  // h ping-pong (2 x 16 MB) in d_out scratch (overwritten by out_k); skip in d_ws.
  float4* h0   = (float4*)out;               // 1,048,576 float4s each
  float4* h1   = (float4*)(out + 4194304);
  float4* skip = (float4*)d_ws;

  dim3 blk(256);
  in_k<<<dim3(512), blk, 0, stream>>>(x, in_w, in_b, h0, skip);

  float4* ha = h0;
  float4* hb = h1;
  for (int l = 0; l < 40; l++) {
    int d = 1 << (l % 10);
    layer_k<<<dim3(512), blk, 0, stream>>>(ha, hb, skip,
        cw + (size_t)l * 2048, cb + l * 32,
        gw + (size_t)l * 2048, gb + l * 32,
        rw + (size_t)l * 1024, rb + l * 32,
        sw + (size_t)l * 1024, sb + l * 32, d);
    float4* tmp = ha; ha = hb; hb = tmp;
  }

  out_k<<<dim3(512), blk, 0, stream>>>(skip, w1, b1, w2, b2, out);
}